// Round 5
// baseline (170.764 us; speedup 1.0000x reference)
//
#include <hip/hip_runtime.h>

// WaveConv3d: B=4, C=32, D=H=W=64, LEVEL=2, m=16.
// Stage 1: s[inp][k][b][c][v16] = (1/8) * WHT3( 2x2x2 sums of 4x4x4 block )
// Stage 2: mixed[k][b][o][v] = sum_i s1*W1 + s2*W2   (per-voxel 32x32 mixing)
// Stage 3: out = (1/8) * invWHT3(mixed) broadcast to 4x4x4 blocks

#define M3 4096        // 16*16*16 voxels
#define KS 524288      // 4*32*M3  : k-stride in s / mixed
#define IS 4194304     // 8*KS     : input-stride in s

// R4 k_fwd: global_load_lds staging (NO dest VGPRs -> compiler cannot
// collapse the load pipeline; R0/R1/R3 all pinned at 104us because RA kept
// VMEM depth at ~1-2). Block = slab (inp,bc,xsl) = 4 d-planes x 64 x 64 =
// 64KB contiguous. 512 threads: 8 gl_lds(16B) per wave, all async in flight,
// one vmcnt(0)+barrier. Global source is PRE-SWIZZLED (g = s ^ (((s>>6)&3)<<1),
// involution on disjoint bits) so stage-2 ds_read_b128 lane->bank classes are
// uniform (8/class = b128 floor) instead of 8-way colliding on the y-stride.
// Stage 2: 2 threads per voxel (hf = d-half), 8x ds_read_b128 + z-pair sums
// -> 4 partials, exchange via ex[], full 8-pt WHT, each half stores 4 subbands.
__global__ __launch_bounds__(512, 4) void k_fwd(const float* __restrict__ x1,
                                                const float* __restrict__ x2,
                                                float* __restrict__ s) {
  const int bid  = blockIdx.x;       // 2*128*16 = 4096 blocks
  const int xsl  = bid & 15;         // x slab index (d-planes 4*xsl..4*xsl+3)
  const int rest = bid >> 4;
  const int bc   = rest & 127;       // b*32+c
  const int inp  = rest >> 7;
  const float* __restrict__ X =
      (inp ? x2 : x1) + (size_t)bc * 262144 + (size_t)xsl * 16384;

  __shared__ __align__(16) float slab[16384];   // 64 KB raw slab (swizzled)
  __shared__ __align__(16) float ex[2][256][4]; // 8 KB partial exchange

  const int tid  = threadIdx.x;
  const int lane = tid & 63;
  const int wv   = tid >> 6;          // 8 waves

  // ---- stage 0: async global->LDS, 8 x 1KB per wave, zero VGPR payload ----
#pragma unroll
  for (int r = 0; r < 8; ++r) {
    const int cn = wv * 8 + r;                       // float4 chunk 0..63
    const int gslot = cn * 64 + (lane ^ ((cn & 3) << 1));  // swizzled source
    __builtin_amdgcn_global_load_lds(
        (const __attribute__((address_space(1))) void*)(X + (size_t)gslot * 4),
        (__attribute__((address_space(3))) void*)(&slab[cn * 256]),
        16, 0, 0);
  }
  __syncthreads();   // drains vmcnt(0) then barrier: slab fully resident

  // ---- stage 1: 2 threads per voxel; hf owns d-planes {2hf, 2hf+1} ----
  const int hf = tid >> 8;            // 0 or 1 (= p of the WHT)
  const int v  = tid & 255;
  const int z = v & 15, y = v >> 4;
  float acc[2][2] = {{0.f, 0.f}, {0.f, 0.f}};   // [q][r]
#pragma unroll
  for (int dp = 0; dp < 2; ++dp) {
    const int dd = 2 * hf + dp;
#pragma unroll
    for (int hh = 0; hh < 4; ++hh) {
      const int row = dd * 64 + 4 * y + hh;
      const int g   = row * 16 + z;                   // raw float4 slot
      const int sp  = g ^ (((g >> 6) & 3) << 1);      // swizzled LDS slot
      const float4 f = *reinterpret_cast<const float4*>(&slab[sp * 4]);
      acc[hh >> 1][0] += f.x + f.y;
      acc[hh >> 1][1] += f.z + f.w;
    }
  }
  // exchange the 4 partials with the partner half
  float4 own;
  own.x = acc[0][0]; own.y = acc[0][1]; own.z = acc[1][0]; own.w = acc[1][1];
  *reinterpret_cast<float4*>(&ex[hf][v][0]) = own;
  __syncthreads();
  const float4 oth = *reinterpret_cast<const float4*>(&ex[hf ^ 1][v][0]);

  const float a0 = hf ? oth.x : own.x, a1 = hf ? oth.y : own.y;
  const float a2 = hf ? oth.z : own.z, a3 = hf ? oth.w : own.w;
  const float a4 = hf ? own.x : oth.x, a5 = hf ? own.y : oth.y;
  const float a6 = hf ? own.z : oth.z, a7 = hf ? own.w : oth.w;
  const float t0 = a0 + a1, t1 = a0 - a1, t2 = a2 + a3, t3 = a2 - a3;
  const float t4 = a4 + a5, t5 = a4 - a5, t6 = a6 + a7, t7 = a6 - a7;
  const float u0 = t0 + t2, u2 = t0 - t2, u1 = t1 + t3, u3 = t1 - t3;
  const float u4 = t4 + t6, u6 = t4 - t6, u5 = t5 + t7, u7 = t5 - t7;
  float* o = s + (size_t)inp * IS + (size_t)bc * M3 + xsl * 256 + y * 16 + z;
  if (hf == 0) {           // subbands 0..3
    o[0 * KS] = 0.125f * (u0 + u4);
    o[1 * KS] = 0.125f * (u1 + u5);
    o[2 * KS] = 0.125f * (u2 + u6);
    o[3 * KS] = 0.125f * (u3 + u7);
  } else {                 // subbands 4..7
    o[4 * KS] = 0.125f * (u0 - u4);
    o[5 * KS] = 0.125f * (u1 - u5);
    o[6 * KS] = 0.125f * (u2 - u6);
    o[7 * KS] = 0.125f * (u3 - u7);
  }
}

__global__ __launch_bounds__(256) void k_mix(const float* __restrict__ W1,
                                             const float* __restrict__ W2,
                                             const float* __restrict__ s,
                                             float* __restrict__ mixed) {
  // 512 blocks: k = bid%8 (XCD-pinned so each subband's 4MiB s-slice stays in one L2)
  const int bid  = blockIdx.x;
  const int k    = bid & 7;
  const int rest = bid >> 3;       // og(4) x vblk(16)
  const int og   = rest & 3;
  const int vblk = rest >> 2;
  const int v = vblk * 256 + threadIdx.x;
  const float* pW1 = W1 + ((size_t)k * 1024 + og * 8) * M3 + v;
  const float* pW2 = W2 + ((size_t)k * 1024 + og * 8) * M3 + v;
  const float* ps  = s + (size_t)k * KS + v;
  float acc[4][8];
#pragma unroll
  for (int b = 0; b < 4; ++b)
#pragma unroll
    for (int oo = 0; oo < 8; ++oo) acc[b][oo] = 0.f;
#pragma unroll 2
  for (int i = 0; i < 32; ++i) {
    float s1b[4], s2b[4];
#pragma unroll
    for (int b = 0; b < 4; ++b) {
      s1b[b] = ps[(size_t)(b * 32 + i) * M3];
      s2b[b] = ps[(size_t)IS + (size_t)(b * 32 + i) * M3];
    }
#pragma unroll
    for (int oo = 0; oo < 8; ++oo) {
      const float w1 = pW1[(size_t)(i * 32 + oo) * M3];
      const float w2 = pW2[(size_t)(i * 32 + oo) * M3];
#pragma unroll
      for (int b = 0; b < 4; ++b) acc[b][oo] += s1b[b] * w1 + s2b[b] * w2;
    }
  }
  float* pm = mixed + (size_t)k * KS + (size_t)og * 8 * M3 + v;
#pragma unroll
  for (int b = 0; b < 4; ++b)
#pragma unroll
    for (int oo = 0; oo < 8; ++oo)
      pm[(size_t)b * (32 * M3) + (size_t)oo * M3] = acc[b][oo];
}

__global__ __launch_bounds__(256) void k_inv(const float* __restrict__ mixed,
                                             float* __restrict__ out) {
  const int tid = blockIdx.x * 256 + threadIdx.x;  // 4*32*4096 threads
  const int v = tid & 4095;
  const int o = (tid >> 12) & 31;
  const int b = tid >> 17;
  const float* pm = mixed + (size_t)(b * 32 + o) * M3 + v;
  const float m0 = pm[0 * (size_t)KS], m1 = pm[1 * (size_t)KS];
  const float m2 = pm[2 * (size_t)KS], m3 = pm[3 * (size_t)KS];
  const float m4 = pm[4 * (size_t)KS], m5 = pm[5 * (size_t)KS];
  const float m6 = pm[6 * (size_t)KS], m7 = pm[7 * (size_t)KS];
  const float t0 = m0 + m1, t1 = m0 - m1, t2 = m2 + m3, t3 = m2 - m3;
  const float t4 = m4 + m5, t5 = m4 - m5, t6 = m6 + m7, t7 = m6 - m7;
  const float u0 = t0 + t2, u2 = t0 - t2, u1 = t1 + t3, u3 = t1 - t3;
  const float u4 = t4 + t6, u6 = t4 - t6, u5 = t5 + t7, u7 = t5 - t7;
  float w[2][2][2];  // w[p][q][r], m = p*4+q*2+r, includes the 1/8
  w[0][0][0] = 0.125f * (u0 + u4);
  w[1][0][0] = 0.125f * (u0 - u4);
  w[0][0][1] = 0.125f * (u1 + u5);
  w[1][0][1] = 0.125f * (u1 - u5);
  w[0][1][0] = 0.125f * (u2 + u6);
  w[1][1][0] = 0.125f * (u2 - u6);
  w[0][1][1] = 0.125f * (u3 + u7);
  w[1][1][1] = 0.125f * (u3 - u7);
  const int z = v & 15, y = (v >> 4) & 15, x = v >> 8;
  float* base =
      out + ((((size_t)(b * 32 + o) * 64 + 4 * x) * 64 + 4 * y) * 64 + 4 * z);
#pragma unroll
  for (int dd = 0; dd < 4; ++dd) {
    const int p = dd >> 1;
#pragma unroll
    for (int hh = 0; hh < 4; ++hh) {
      const int q = hh >> 1;
      const float lo = w[p][q][0], hi = w[p][q][1];
      float4 f;
      f.x = lo; f.y = lo; f.z = hi; f.w = hi;
      *reinterpret_cast<float4*>(base + (dd * 64 + hh) * 64) = f;
    }
  }
}

extern "C" void kernel_launch(void* const* d_in, const int* in_sizes, int n_in,
                              void* d_out, int out_size, void* d_ws, size_t ws_size,
                              hipStream_t stream) {
  const float* x1 = (const float*)d_in[0];
  const float* x2 = (const float*)d_in[1];
  const float* W1 = (const float*)d_in[2];
  const float* W2 = (const float*)d_in[3];
  float* out = (float*)d_out;
  float* s     = (float*)d_ws;             // 2*IS floats = 32 MiB
  float* mixed = s + 2 * (size_t)IS;       // IS floats   = 16 MiB
  k_fwd<<<4096, 512, 0, stream>>>(x1, x2, s);
  k_mix<<<512, 256, 0, stream>>>(W1, W2, s, mixed);
  k_inv<<<2048, 256, 0, stream>>>(mixed, out);
}

// Round 6
// 165.154 us; speedup vs baseline: 1.0340x; 1.0340x over previous
//
#include <hip/hip_runtime.h>

// WaveConv3d: B=4, C=32, D=H=W=64, LEVEL=2, m=16.
// Stage 1: s[inp][k][b][c][v16] = (1/8) * WHT3( 2x2x2 sums of 4x4x4 block )
// Stage 2: mixed[k][b][o][v] = sum_i s1*W1 + s2*W2   (per-voxel 32x32 mixing)
// Stage 3: out = (1/8) * invWHT3(mixed) broadcast to 4x4x4 blocks

#define M3 4096        // 16*16*16 voxels
#define KS 524288      // 4*32*M3  : k-stride in s / mixed
#define IS 4194304     // 8*KS     : input-stride in s
#define NSLAB 16

// R5 k_fwd: persistent double-buffered pipeline (T3/T4-lite).
//  R0-R4 history: 104us regardless of structure (reg-loads, LDS staging,
//  gl_lds staging). R4 proved depth isn't the limiter (async gl_lds, 0
//  conflicts, still 100us). Diagnosis: burst-and-drain — every block issues
//  64KB then ALL waves wait vmcnt(0) at a barrier; machine-wide ~32MB bursts
//  queue up (~5us effective latency), then the pipe idles during compute +
//  block relaunch -> ~50% duty cycle (observed 6.25us per 64KB per CU vs
//  2.7us share-limited).
//  Fix: 256 persistent blocks (1/CU, 128KB LDS = 2x64KB slab buffers); each
//  block scans its (inp,bc) volume linearly over 16 slabs. Stage slab t+1,
//  s_waitcnt vmcnt(8) (slab t landed, t+1 in flight), RAW s_barrier (NOT
//  __syncthreads -- that drains vmcnt(0)), compute slab t, barrier. The load
//  pipe never idles. Same reduction math/swizzle as R4 (verified, 0 bank
//  conflicts): source pre-swizzled g^(((g>>6)&3)<<1) so ds_read_b128 classes
//  are uniform; gl_lds dest stays linear (wave-uniform base + lane*16).
__global__ __launch_bounds__(512) void k_fwd(const float* __restrict__ x1,
                                             const float* __restrict__ x2,
                                             float* __restrict__ s) {
  const int blk = blockIdx.x;          // 256 blocks: inp*128 + bc
  const int bc  = blk & 127;
  const int inp = blk >> 7;
  const float* __restrict__ X = (inp ? x2 : x1) + (size_t)bc * 262144;

  __shared__ __align__(16) float buf[2][16384];   // 2 x 64 KB

  const int tid  = threadIdx.x;
  const int lane = tid & 63;
  const int wv   = tid >> 6;           // 8 waves

  auto stage = [&](int xsl, int bi) {
#pragma unroll
    for (int r = 0; r < 8; ++r) {
      const int cn = wv * 8 + r;                          // 1KB chunk 0..63
      const int gslot = cn * 64 + (lane ^ ((cn & 3) << 1));   // swizzled src
      __builtin_amdgcn_global_load_lds(
          (const __attribute__((address_space(1))) void*)(
              X + (size_t)xsl * 16384 + (size_t)gslot * 4),
          (__attribute__((address_space(3))) void*)(&buf[bi][cn * 256]),
          16, 0, 0);
    }
  };

  stage(0, 0);
  for (int t = 0; t < NSLAB; ++t) {
    if (t + 1 < NSLAB) {
      stage(t + 1, (t + 1) & 1);
      // slab t's 8 loads (oldest) done; slab t+1's 8 stay in flight.
      asm volatile("s_waitcnt vmcnt(8)" ::: "memory");
    } else {
      asm volatile("s_waitcnt vmcnt(0)" ::: "memory");
    }
    __builtin_amdgcn_s_barrier();
    __builtin_amdgcn_sched_barrier(0);

    if (tid < 256) {                   // waves 0-3 compute; 4-7 only stage
      const int z = tid & 15, y = tid >> 4;
      const float* bp = buf[t & 1];
      float acc[2][2][2] = {{{0.f, 0.f}, {0.f, 0.f}}, {{0.f, 0.f}, {0.f, 0.f}}};
#pragma unroll
      for (int dd = 0; dd < 4; ++dd) {
#pragma unroll
        for (int hh = 0; hh < 4; ++hh) {
          const int row = dd * 64 + 4 * y + hh;
          const int g   = row * 16 + z;                 // raw float4 slot
          const int sp  = g ^ (((g >> 6) & 3) << 1);    // swizzled LDS slot
          const float4 f = *reinterpret_cast<const float4*>(&bp[sp * 4]);
          acc[dd >> 1][hh >> 1][0] += f.x + f.y;
          acc[dd >> 1][hh >> 1][1] += f.z + f.w;
        }
      }
      const float a0 = acc[0][0][0], a1 = acc[0][0][1], a2 = acc[0][1][0], a3 = acc[0][1][1];
      const float a4 = acc[1][0][0], a5 = acc[1][0][1], a6 = acc[1][1][0], a7 = acc[1][1][1];
      const float t0 = a0 + a1, t1 = a0 - a1, t2 = a2 + a3, t3 = a2 - a3;
      const float t4 = a4 + a5, t5 = a4 - a5, t6 = a6 + a7, t7 = a6 - a7;
      const float u0 = t0 + t2, u2 = t0 - t2, u1 = t1 + t3, u3 = t1 - t3;
      const float u4 = t4 + t6, u6 = t4 - t6, u5 = t5 + t7, u7 = t5 - t7;
      float* o = s + (size_t)inp * IS + (size_t)bc * M3 + t * 256 + y * 16 + z;
      o[0 * KS] = 0.125f * (u0 + u4);
      o[4 * KS] = 0.125f * (u0 - u4);
      o[1 * KS] = 0.125f * (u1 + u5);
      o[5 * KS] = 0.125f * (u1 - u5);
      o[2 * KS] = 0.125f * (u2 + u6);
      o[6 * KS] = 0.125f * (u2 - u6);
      o[3 * KS] = 0.125f * (u3 + u7);
      o[7 * KS] = 0.125f * (u3 - u7);
    }
    __builtin_amdgcn_sched_barrier(0);
    __builtin_amdgcn_s_barrier();      // all reads of buf[t&1] done before
  }                                    // iter t+1 stages into it
}

__global__ __launch_bounds__(256) void k_mix(const float* __restrict__ W1,
                                             const float* __restrict__ W2,
                                             const float* __restrict__ s,
                                             float* __restrict__ mixed) {
  // 512 blocks: k = bid%8 (XCD-pinned so each subband's 4MiB s-slice stays in one L2)
  const int bid  = blockIdx.x;
  const int k    = bid & 7;
  const int rest = bid >> 3;       // og(4) x vblk(16)
  const int og   = rest & 3;
  const int vblk = rest >> 2;
  const int v = vblk * 256 + threadIdx.x;
  const float* pW1 = W1 + ((size_t)k * 1024 + og * 8) * M3 + v;
  const float* pW2 = W2 + ((size_t)k * 1024 + og * 8) * M3 + v;
  const float* ps  = s + (size_t)k * KS + v;
  float acc[4][8];
#pragma unroll
  for (int b = 0; b < 4; ++b)
#pragma unroll
    for (int oo = 0; oo < 8; ++oo) acc[b][oo] = 0.f;
#pragma unroll 2
  for (int i = 0; i < 32; ++i) {
    float s1b[4], s2b[4];
#pragma unroll
    for (int b = 0; b < 4; ++b) {
      s1b[b] = ps[(size_t)(b * 32 + i) * M3];
      s2b[b] = ps[(size_t)IS + (size_t)(b * 32 + i) * M3];
    }
#pragma unroll
    for (int oo = 0; oo < 8; ++oo) {
      const float w1 = pW1[(size_t)(i * 32 + oo) * M3];
      const float w2 = pW2[(size_t)(i * 32 + oo) * M3];
#pragma unroll
      for (int b = 0; b < 4; ++b) acc[b][oo] += s1b[b] * w1 + s2b[b] * w2;
    }
  }
  float* pm = mixed + (size_t)k * KS + (size_t)og * 8 * M3 + v;
#pragma unroll
  for (int b = 0; b < 4; ++b)
#pragma unroll
    for (int oo = 0; oo < 8; ++oo)
      pm[(size_t)b * (32 * M3) + (size_t)oo * M3] = acc[b][oo];
}

__global__ __launch_bounds__(256) void k_inv(const float* __restrict__ mixed,
                                             float* __restrict__ out) {
  const int tid = blockIdx.x * 256 + threadIdx.x;  // 4*32*4096 threads
  const int v = tid & 4095;
  const int o = (tid >> 12) & 31;
  const int b = tid >> 17;
  const float* pm = mixed + (size_t)(b * 32 + o) * M3 + v;
  const float m0 = pm[0 * (size_t)KS], m1 = pm[1 * (size_t)KS];
  const float m2 = pm[2 * (size_t)KS], m3 = pm[3 * (size_t)KS];
  const float m4 = pm[4 * (size_t)KS], m5 = pm[5 * (size_t)KS];
  const float m6 = pm[6 * (size_t)KS], m7 = pm[7 * (size_t)KS];
  const float t0 = m0 + m1, t1 = m0 - m1, t2 = m2 + m3, t3 = m2 - m3;
  const float t4 = m4 + m5, t5 = m4 - m5, t6 = m6 + m7, t7 = m6 - m7;
  const float u0 = t0 + t2, u2 = t0 - t2, u1 = t1 + t3, u3 = t1 - t3;
  const float u4 = t4 + t6, u6 = t4 - t6, u5 = t5 + t7, u7 = t5 - t7;
  float w[2][2][2];  // w[p][q][r], m = p*4+q*2+r, includes the 1/8
  w[0][0][0] = 0.125f * (u0 + u4);
  w[1][0][0] = 0.125f * (u0 - u4);
  w[0][0][1] = 0.125f * (u1 + u5);
  w[1][0][1] = 0.125f * (u1 - u5);
  w[0][1][0] = 0.125f * (u2 + u6);
  w[1][1][0] = 0.125f * (u2 - u6);
  w[0][1][1] = 0.125f * (u3 + u7);
  w[1][1][1] = 0.125f * (u3 - u7);
  const int z = v & 15, y = (v >> 4) & 15, x = v >> 8;
  float* base =
      out + ((((size_t)(b * 32 + o) * 64 + 4 * x) * 64 + 4 * y) * 64 + 4 * z);
#pragma unroll
  for (int dd = 0; dd < 4; ++dd) {
    const int p = dd >> 1;
#pragma unroll
    for (int hh = 0; hh < 4; ++hh) {
      const int q = hh >> 1;
      const float lo = w[p][q][0], hi = w[p][q][1];
      float4 f;
      f.x = lo; f.y = lo; f.z = hi; f.w = hi;
      *reinterpret_cast<float4*>(base + (dd * 64 + hh) * 64) = f;
    }
  }
}

extern "C" void kernel_launch(void* const* d_in, const int* in_sizes, int n_in,
                              void* d_out, int out_size, void* d_ws, size_t ws_size,
                              hipStream_t stream) {
  const float* x1 = (const float*)d_in[0];
  const float* x2 = (const float*)d_in[1];
  const float* W1 = (const float*)d_in[2];
  const float* W2 = (const float*)d_in[3];
  float* out = (float*)d_out;
  float* s     = (float*)d_ws;             // 2*IS floats = 32 MiB
  float* mixed = s + 2 * (size_t)IS;       // IS floats   = 16 MiB
  k_fwd<<<256, 512, 0, stream>>>(x1, x2, s);
  k_mix<<<512, 256, 0, stream>>>(W1, W2, s, mixed);
  k_inv<<<2048, 256, 0, stream>>>(mixed, out);
}